// Round 4
// baseline (970.118 us; speedup 1.0000x reference)
//
#include <hip/hip_runtime.h>
#include <hip/hip_bf16.h>

// CTC forward loss, T=4096, C=8192, L=512 -> S=1025 states.
// Phase A (ctc_emit): per-row log2-softmax + gather at the 1025 extended
//   states, normalized per row (max=1, offset c_t), bf16. Uses raw v_exp_f32
//   (__builtin_amdgcn_exp2f) -- libm exp2f's fixup code made emit VALU-bound.
// Phase B (ctc_scan1w): single-wave linear-domain alpha recursion, per-lane
//   block-floating-point scale (verified exact in R3). The boundary shfl is
//   software-pipelined one step ahead: B[15]/B16 computed first, shfl issued,
//   B[0..14] computed while the ds_permute is in flight.

#define T_STEPS 4096
#define N_CLASSES 8192
#define S_TOT 1025
#define PSTRIDE 1026              // elements per P row (pad to even)
#define PROWB (PSTRIDE * 2)       // 2052 bytes per bf16 row
#define INV_LN2 1.4426950408889634f
#define LN2F 0.6931471805599453f

static __device__ __forceinline__ float wredMax(float v) {
#pragma unroll
  for (int d = 32; d >= 1; d >>= 1) v = fmaxf(v, __shfl_xor(v, d, 64));
  return v;
}
static __device__ __forceinline__ float wredSum(float v) {
#pragma unroll
  for (int d = 32; d >= 1; d >>= 1) v += __shfl_xor(v, d, 64);
  return v;
}

#define FEXP2(x) __builtin_amdgcn_exp2f(x)
#define FLOG2(x) __builtin_amdgcn_logf(x)

// ---------------- Phase A: emissions ----------------
__global__ __launch_bounds__(256) void ctc_emit(const float* __restrict__ logits,
                                                const int* __restrict__ targets,
                                                __hip_bfloat16* __restrict__ P,
                                                float* __restrict__ cvec) {
  __shared__ __align__(16) float row[N_CLASSES];
  __shared__ float red[4];
  const int t = blockIdx.x;
  const int tid = threadIdx.x;
  const int lane = tid & 63, wid = tid >> 6;
  const float4* src = (const float4*)(logits + (size_t)t * N_CLASSES);

  float4 v[8];
  float lmax = -3.0e38f;
#pragma unroll
  for (int k = 0; k < 8; ++k) {
    v[k] = src[tid + 256 * k];
    ((float4*)row)[tid + 256 * k] = v[k];
    lmax = fmaxf(lmax, fmaxf(fmaxf(v[k].x, v[k].y), fmaxf(v[k].z, v[k].w)));
  }
  lmax = wredMax(lmax);
  if (lane == 0) red[wid] = lmax;
  __syncthreads();
  const float rowmax = fmaxf(fmaxf(red[0], red[1]), fmaxf(red[2], red[3]));
  const float m2 = rowmax * INV_LN2;

  float acc = 0.f;
#pragma unroll
  for (int k = 0; k < 8; ++k) {
    acc += FEXP2(fmaf(v[k].x, INV_LN2, -m2));
    acc += FEXP2(fmaf(v[k].y, INV_LN2, -m2));
    acc += FEXP2(fmaf(v[k].z, INV_LN2, -m2));
    acc += FEXP2(fmaf(v[k].w, INV_LN2, -m2));
  }
  acc = wredSum(acc);
  __syncthreads();
  if (lane == 0) red[wid] = acc;
  __syncthreads();
  const float Z = red[0] + red[1] + red[2] + red[3];
  const float denom2 = m2 + FLOG2(Z);   // lp2[c] = x[c]/ln2 - denom2

  float e2v[5];
  float gmax = -3.0e38f;
#pragma unroll
  for (int k = 0; k < 5; ++k) {
    int s = tid + 256 * k;
    if (s < S_TOT) {
      int cls = (s & 1) ? targets[(s - 1) >> 1] : 0;   // even states = blank(0)
      float e2 = fmaf(row[cls], INV_LN2, -denom2);
      e2v[k] = e2;
      gmax = fmaxf(gmax, e2);
    }
  }
  gmax = wredMax(gmax);
  __syncthreads();
  if (lane == 0) red[wid] = gmax;
  __syncthreads();
  const float ct = fmaxf(fmaxf(red[0], red[1]), fmaxf(red[2], red[3]));

  __hip_bfloat16* Prow = P + (size_t)t * PSTRIDE;
#pragma unroll
  for (int k = 0; k < 5; ++k) {
    int s = tid + 256 * k;
    if (s < S_TOT) Prow[s] = __float2bfloat16(FEXP2(e2v[k] - ct));
  }
  if (tid == 0) cvec[t] = ct;
}

// ---------------- Phase B: single-wave scan, per-lane scale ----------------
__global__ __launch_bounds__(64, 1) void ctc_scan1w(const char* __restrict__ Pb,
                                                    const float* __restrict__ cvec,
                                                    const int* __restrict__ targets,
                                                    float* __restrict__ out) {
  const int lane = threadIdx.x;

  // allow-skip flags for odd local states j=2k+1 (global s=16*lane+2k+1)
  float al[8];
#pragma unroll
  for (int k = 0; k < 8; ++k) {
    int li = 8 * lane + k;
    int c = targets[li];
    int cm1 = (li == 0) ? -1 : targets[li - 1];
    al[k] = (c != 0 && c != cm1) ? 1.0f : 0.0f;
  }

  // sum of per-row log2 normalization offsets
  float sc = 0.f;
  for (int i = lane; i < T_STEPS; i += 64) sc += cvec[i];
  sc = wredSum(sc);

  // state registers
  float a[16], b[16], a16 = 0.f, b16;
#pragma unroll
  for (int j = 0; j < 16; ++j) a[j] = 0.f;
  if (lane == 0) {
    unsigned int pv0 = *(const unsigned int*)(Pb);
    a[0] = __uint_as_float((pv0 & 0xFFFFu) << 16);
    a[1] = __uint_as_float(pv0 & 0xFFFF0000u);
  }
  int omega = 0;   // per-lane: stored = true * 2^omega
  int wprev = 0;   // upstream lane's omega (refreshed at each rescale)
  int wd = 0;      // omega - wprev

  // prime boundary pipeline: value for step t=1
  float Lraw = __shfl_up(a[15], 1, 64);

  // prefetch ring, depth 8: rows t..t+7. 32 B/lane + broadcast u16 (state 1024)
  uint4 q0[8], q1[8];
  unsigned short qe[8];
  const char* myp = Pb + 32 * lane;
#pragma unroll
  for (int j = 0; j < 8; ++j) {
    const char* rp = myp + (size_t)(1 + j) * PROWB;
    q0[j] = *(const uint4*)(rp);
    q1[j] = *(const uint4*)(rp + 16);
    qe[j] = *(const unsigned short*)(Pb + (size_t)(1 + j) * PROWB + 2048);
  }

  int t = 1;

#define UNPK_LO(u) __uint_as_float((u) << 16)
#define UNPK_HI(u) __uint_as_float((u) & 0xFFFF0000u)

#define BODY_MID(A, B, x0, x1)                                                 \
    B[2] = (A[2] + A[1]) * UNPK_LO(x0.y);                                      \
    B[3] = fmaf(al[1], A[1], A[3] + A[2]) * UNPK_HI(x0.y);                     \
    B[4] = (A[4] + A[3]) * UNPK_LO(x0.z);                                      \
    B[5] = fmaf(al[2], A[3], A[5] + A[4]) * UNPK_HI(x0.z);                     \
    B[6] = (A[6] + A[5]) * UNPK_LO(x0.w);                                      \
    B[7] = fmaf(al[3], A[5], A[7] + A[6]) * UNPK_HI(x0.w);                     \
    B[8] = (A[8] + A[7]) * UNPK_LO(x1.x);                                      \
    B[9] = fmaf(al[4], A[7], A[9] + A[8]) * UNPK_HI(x1.x);                     \
    B[10] = (A[10] + A[9]) * UNPK_LO(x1.y);                                    \
    B[11] = fmaf(al[5], A[9], A[11] + A[10]) * UNPK_HI(x1.y);                  \
    B[12] = (A[12] + A[11]) * UNPK_LO(x1.z);                                   \
    B[13] = fmaf(al[6], A[11], A[13] + A[12]) * UNPK_HI(x1.z);                 \
    B[14] = (A[14] + A[13]) * UNPK_LO(x1.w);

#define PREF(slot)                                                             \
    {                                                                          \
      const char* rp = myp + (size_t)(t + 8) * PROWB;                          \
      q0[slot] = *(const uint4*)(rp);                                          \
      q1[slot] = *(const uint4*)(rp + 16);                                     \
      qe[slot] = *(const unsigned short*)(Pb + (size_t)(t + 8) * PROWB + 2048);\
    }

  // Fast step: top states first, issue next-step shfl, then the rest.
#define STEPF(A, A16, B, B16)                                                  \
  {                                                                            \
    const int slot = (t - 1) & 7;                                              \
    const uint4 x0 = q0[slot];                                                 \
    const uint4 x1 = q1[slot];                                                 \
    const unsigned int xe = qe[slot];                                          \
    PREF(slot);                                                                \
    B[15] = fmaf(al[7], A[13], A[15] + A[14]) * UNPK_HI(x1.w);                 \
    B16 = (lane == 63) ? (A16 + A[15]) * UNPK_LO(xe) : 0.f;                    \
    float newL = __shfl_up(B[15], 1, 64);                                      \
    float La = (lane == 0) ? 0.f : ldexpf(Lraw, wd);                           \
    B[0] = (A[0] + La) * UNPK_LO(x0.x);                                        \
    B[1] = fmaf(al[0], La, A[1] + A[0]) * UNPK_HI(x0.x);                       \
    BODY_MID(A, B, x0, x1)                                                     \
    Lraw = newL;                                                               \
    ++t;                                                                       \
  }

  // Rescale step (every 8th): compute all, per-lane rescale, refresh wd, send.
#define STEPS_(A, A16, B, B16)                                                 \
  {                                                                            \
    const int slot = (t - 1) & 7;                                              \
    const uint4 x0 = q0[slot];                                                 \
    const uint4 x1 = q1[slot];                                                 \
    const unsigned int xe = qe[slot];                                          \
    PREF(slot);                                                                \
    float La = (lane == 0) ? 0.f : ldexpf(Lraw, wd);                           \
    B[15] = fmaf(al[7], A[13], A[15] + A[14]) * UNPK_HI(x1.w);                 \
    B16 = (lane == 63) ? (A16 + A[15]) * UNPK_LO(xe) : 0.f;                    \
    B[0] = (A[0] + La) * UNPK_LO(x0.x);                                        \
    B[1] = fmaf(al[0], La, A[1] + A[0]) * UNPK_HI(x0.x);                       \
    BODY_MID(A, B, x0, x1)                                                     \
    float m = 0.f;                                                             \
    _Pragma("unroll") for (int j = 0; j < 16; ++j) m = fmaxf(m, B[j]);         \
    if (lane == 63) m = fmaxf(m, B16);                                         \
    if (m > 0.f) {                                                             \
      int e = (int)((__float_as_uint(m) >> 23) & 255u);                        \
      int shift = 127 - e;                                                     \
      _Pragma("unroll") for (int j = 0; j < 16; ++j) B[j] = ldexpf(B[j], shift); \
      B16 = ldexpf(B16, shift);                                                \
      omega += shift;                                                          \
    } else {                                                                   \
      omega = wprev;                                                           \
    }                                                                          \
    wprev = __shfl_up(omega, 1, 64);                                           \
    wd = omega - wprev;                                                        \
    Lraw = __shfl_up(B[15], 1, 64);                                            \
    ++t;                                                                       \
  }

  for (int g = 0; g < 511; ++g) {   // steps t = 8g+1 .. 8g+8 (1..4088)
    STEPF(a, a16, b, b16);
    STEPF(b, b16, a, a16);
    STEPF(a, a16, b, b16);
    STEPF(b, b16, a, a16);
    STEPF(a, a16, b, b16);
    STEPF(b, b16, a, a16);
    STEPF(a, a16, b, b16);
    STEPS_(b, b16, a, a16);          // rescale at t = 8g+8; ends in a
  }
  // steps t = 4089 .. 4095 (7 steps; result ends in b)
  STEPF(a, a16, b, b16);
  STEPF(b, b16, a, a16);
  STEPF(a, a16, b, b16);
  STEPF(b, b16, a, a16);
  STEPF(a, a16, b, b16);
  STEPF(b, b16, a, a16);
  STEPF(a, a16, b, b16);

  if (lane == 63) {
    // states 1023 (b[15]) and 1024 (b16), lane-63 scale: 2^(sc - omega)
    float tot = b[15] + b16;
    out[0] = -LN2F * (FLOG2(tot) + sc - (float)omega);
  }
}

extern "C" void kernel_launch(void* const* d_in, const int* in_sizes, int n_in,
                              void* d_out, int out_size, void* d_ws, size_t ws_size,
                              hipStream_t stream) {
  (void)in_sizes; (void)n_in; (void)out_size; (void)ws_size;
  const float* logits = (const float*)d_in[0];
  const int* targets = (const int*)d_in[1];
  // ws layout: P bf16 [4096 x 1026] (8,404,992 B) | 64 rows slack (prefetch
  // overrun, contents unused) | cvec f32[4096]
  char* ws = (char*)d_ws;
  __hip_bfloat16* P = (__hip_bfloat16*)ws;
  float* cvec = (float*)(ws + (size_t)T_STEPS * PROWB + 64 * PROWB);

  ctc_emit<<<dim3(T_STEPS), dim3(256), 0, stream>>>(logits, targets, P, cvec);
  ctc_scan1w<<<dim3(1), dim3(64), 0, stream>>>((const char*)P, cvec, targets,
                                               (float*)d_out);
}

// Round 5
// 830.408 us; speedup vs baseline: 1.1682x; 1.1682x over previous
//
#include <hip/hip_runtime.h>
#include <hip/hip_bf16.h>

// CTC forward loss, T=4096, C=8192, L=512 -> S=1025 states.
// Phase A (ctc_emit): per-row log2-softmax + gather at the 1025 extended
//   states, normalized per row (max=1, offset c_t), bf16.
// Phase B (ctc_scan1w): single-wave linear-domain alpha recursion, per-lane
//   block-floating-point scale (exact; R3/R4 absmax=0). R5: prefetch ring as
//   NAMED variables -- R3/R4 used arrays with dynamic slot index, which LLVM
//   demoted to scratch (VGPR_Count=72 proved it), making every step pay
//   full memory latency through private-memory traffic.

#define T_STEPS 4096
#define N_CLASSES 8192
#define S_TOT 1025
#define PSTRIDE 1026              // elements per P row (pad to even)
#define PROWB (PSTRIDE * 2)       // 2052 bytes per bf16 row
#define INV_LN2 1.4426950408889634f
#define LN2F 0.6931471805599453f

static __device__ __forceinline__ float wredMax(float v) {
#pragma unroll
  for (int d = 32; d >= 1; d >>= 1) v = fmaxf(v, __shfl_xor(v, d, 64));
  return v;
}
static __device__ __forceinline__ float wredSum(float v) {
#pragma unroll
  for (int d = 32; d >= 1; d >>= 1) v += __shfl_xor(v, d, 64);
  return v;
}

#define FEXP2(x) __builtin_amdgcn_exp2f(x)
#define FLOG2(x) __builtin_amdgcn_logf(x)

// ---------------- Phase A: emissions ----------------
__global__ __launch_bounds__(256) void ctc_emit(const float* __restrict__ logits,
                                                const int* __restrict__ targets,
                                                __hip_bfloat16* __restrict__ P,
                                                float* __restrict__ cvec) {
  __shared__ __align__(16) float row[N_CLASSES];
  __shared__ float red[4];
  const int t = blockIdx.x;
  const int tid = threadIdx.x;
  const int lane = tid & 63, wid = tid >> 6;
  const float4* src = (const float4*)(logits + (size_t)t * N_CLASSES);

  float4 v[8];
  float lmax = -3.0e38f;
#pragma unroll
  for (int k = 0; k < 8; ++k) {
    v[k] = src[tid + 256 * k];
    ((float4*)row)[tid + 256 * k] = v[k];
    lmax = fmaxf(lmax, fmaxf(fmaxf(v[k].x, v[k].y), fmaxf(v[k].z, v[k].w)));
  }
  lmax = wredMax(lmax);
  if (lane == 0) red[wid] = lmax;
  __syncthreads();
  const float rowmax = fmaxf(fmaxf(red[0], red[1]), fmaxf(red[2], red[3]));
  const float m2 = rowmax * INV_LN2;

  float acc = 0.f;
#pragma unroll
  for (int k = 0; k < 8; ++k) {
    acc += FEXP2(fmaf(v[k].x, INV_LN2, -m2));
    acc += FEXP2(fmaf(v[k].y, INV_LN2, -m2));
    acc += FEXP2(fmaf(v[k].z, INV_LN2, -m2));
    acc += FEXP2(fmaf(v[k].w, INV_LN2, -m2));
  }
  acc = wredSum(acc);
  __syncthreads();
  if (lane == 0) red[wid] = acc;
  __syncthreads();
  const float Z = red[0] + red[1] + red[2] + red[3];
  const float denom2 = m2 + FLOG2(Z);   // lp2[c] = x[c]/ln2 - denom2

  float e2v[5];
  float gmax = -3.0e38f;
#pragma unroll
  for (int k = 0; k < 5; ++k) {
    int s = tid + 256 * k;
    if (s < S_TOT) {
      int cls = (s & 1) ? targets[(s - 1) >> 1] : 0;   // even states = blank(0)
      float e2 = fmaf(row[cls], INV_LN2, -denom2);
      e2v[k] = e2;
      gmax = fmaxf(gmax, e2);
    }
  }
  gmax = wredMax(gmax);
  __syncthreads();
  if (lane == 0) red[wid] = gmax;
  __syncthreads();
  const float ct = fmaxf(fmaxf(red[0], red[1]), fmaxf(red[2], red[3]));

  __hip_bfloat16* Prow = P + (size_t)t * PSTRIDE;
#pragma unroll
  for (int k = 0; k < 5; ++k) {
    int s = tid + 256 * k;
    if (s < S_TOT) Prow[s] = __float2bfloat16(FEXP2(e2v[k] - ct));
  }
  if (tid == 0) cvec[t] = ct;
}

// ---------------- Phase B: single-wave scan, per-lane scale ----------------
__global__ __launch_bounds__(64, 1) void ctc_scan1w(const char* __restrict__ Pb,
                                                    const float* __restrict__ cvec,
                                                    const int* __restrict__ targets,
                                                    float* __restrict__ out) {
  const int lane = threadIdx.x;

  // allow-skip flags for odd local states j=2k+1 (global s=16*lane+2k+1)
  float al[8];
#pragma unroll
  for (int k = 0; k < 8; ++k) {
    int li = 8 * lane + k;
    int c = targets[li];
    int cm1 = (li == 0) ? -1 : targets[li - 1];
    al[k] = (c != 0 && c != cm1) ? 1.0f : 0.0f;
  }

  // sum of per-row log2 normalization offsets
  float sc = 0.f;
  for (int i = lane; i < T_STEPS; i += 64) sc += cvec[i];
  sc = wredSum(sc);

  // state registers
  float a[16], b[16], a16 = 0.f, b16;
#pragma unroll
  for (int j = 0; j < 16; ++j) a[j] = 0.f;
  if (lane == 0) {
    unsigned int pv0 = *(const unsigned int*)(Pb);
    a[0] = __uint_as_float((pv0 & 0xFFFFu) << 16);
    a[1] = __uint_as_float(pv0 & 0xFFFF0000u);
  }
  int omega = 0;   // per-lane: stored = true * 2^omega
  int wprev = 0;   // upstream lane's omega (refreshed at each rescale)
  int wd = 0;      // omega - wprev

  // prime boundary pipeline: value for step t=1
  float Lraw = __shfl_up(a[15], 1, 64);

  const char* myp = Pb + 32 * lane;

  // prefetch ring, depth 8, as NAMED variables (no dynamic indexing ->
  // stays in VGPRs). Slot k holds row t0+k; refilled in unroll position k.
  uint4 qa0, qb0, qa1, qb1, qa2, qb2, qa3, qb3;
  uint4 qa4, qb4, qa5, qb5, qa6, qb6, qa7, qb7;
  unsigned short e0, e1, e2, e3, e4, e5, e6, e7;

#define PRIME(J, QA, QB, QE)                                                   \
  {                                                                            \
    const char* rp = myp + (size_t)(1 + J) * PROWB;                            \
    QA = *(const uint4*)(rp);                                                  \
    QB = *(const uint4*)(rp + 16);                                             \
    QE = *(const unsigned short*)(Pb + (size_t)(1 + J) * PROWB + 2048);        \
  }
  PRIME(0, qa0, qb0, e0)
  PRIME(1, qa1, qb1, e1)
  PRIME(2, qa2, qb2, e2)
  PRIME(3, qa3, qb3, e3)
  PRIME(4, qa4, qb4, e4)
  PRIME(5, qa5, qb5, e5)
  PRIME(6, qa6, qb6, e6)
  PRIME(7, qa7, qb7, e7)

  int t = 1;

#define UNPK_LO(u) __uint_as_float((u) << 16)
#define UNPK_HI(u) __uint_as_float((u) & 0xFFFF0000u)

#define BODY_MID(A, B, x0, x1)                                                 \
    B[2] = (A[2] + A[1]) * UNPK_LO(x0.y);                                      \
    B[3] = fmaf(al[1], A[1], A[3] + A[2]) * UNPK_HI(x0.y);                     \
    B[4] = (A[4] + A[3]) * UNPK_LO(x0.z);                                      \
    B[5] = fmaf(al[2], A[3], A[5] + A[4]) * UNPK_HI(x0.z);                     \
    B[6] = (A[6] + A[5]) * UNPK_LO(x0.w);                                      \
    B[7] = fmaf(al[3], A[5], A[7] + A[6]) * UNPK_HI(x0.w);                     \
    B[8] = (A[8] + A[7]) * UNPK_LO(x1.x);                                      \
    B[9] = fmaf(al[4], A[7], A[9] + A[8]) * UNPK_HI(x1.x);                     \
    B[10] = (A[10] + A[9]) * UNPK_LO(x1.y);                                    \
    B[11] = fmaf(al[5], A[9], A[11] + A[10]) * UNPK_HI(x1.y);                  \
    B[12] = (A[12] + A[11]) * UNPK_LO(x1.z);                                   \
    B[13] = fmaf(al[6], A[11], A[13] + A[12]) * UNPK_HI(x1.z);                 \
    B[14] = (A[14] + A[13]) * UNPK_LO(x1.w);

#define PREFN(QA, QB, QE)                                                      \
    {                                                                          \
      const char* rp = myp + (size_t)(t + 8) * PROWB;                          \
      QA = *(const uint4*)(rp);                                                \
      QB = *(const uint4*)(rp + 16);                                           \
      QE = *(const unsigned short*)(Pb + (size_t)(t + 8) * PROWB + 2048);      \
    }

  // Fast step: top states first, issue next-step shfl, then the rest.
#define STEPF_N(A, A16, B, B16, QA, QB, QE)                                    \
  {                                                                            \
    const uint4 x0 = QA;                                                       \
    const uint4 x1 = QB;                                                       \
    const unsigned int xe = QE;                                                \
    PREFN(QA, QB, QE);                                                         \
    B[15] = fmaf(al[7], A[13], A[15] + A[14]) * UNPK_HI(x1.w);                 \
    B16 = (lane == 63) ? (A16 + A[15]) * UNPK_LO(xe) : 0.f;                    \
    float newL = __shfl_up(B[15], 1, 64);                                      \
    float La = (lane == 0) ? 0.f : ldexpf(Lraw, wd);                           \
    B[0] = (A[0] + La) * UNPK_LO(x0.x);                                        \
    B[1] = fmaf(al[0], La, A[1] + A[0]) * UNPK_HI(x0.x);                       \
    BODY_MID(A, B, x0, x1)                                                     \
    Lraw = newL;                                                               \
    ++t;                                                                       \
  }

  // Rescale step (every 8th): compute all, per-lane rescale, refresh wd, send.
#define STEPS_N(A, A16, B, B16, QA, QB, QE)                                    \
  {                                                                            \
    const uint4 x0 = QA;                                                       \
    const uint4 x1 = QB;                                                       \
    const unsigned int xe = QE;                                                \
    PREFN(QA, QB, QE);                                                         \
    float La = (lane == 0) ? 0.f : ldexpf(Lraw, wd);                           \
    B[15] = fmaf(al[7], A[13], A[15] + A[14]) * UNPK_HI(x1.w);                 \
    B16 = (lane == 63) ? (A16 + A[15]) * UNPK_LO(xe) : 0.f;                    \
    B[0] = (A[0] + La) * UNPK_LO(x0.x);                                        \
    B[1] = fmaf(al[0], La, A[1] + A[0]) * UNPK_HI(x0.x);                       \
    BODY_MID(A, B, x0, x1)                                                     \
    float m = 0.f;                                                             \
    _Pragma("unroll") for (int j = 0; j < 16; ++j) m = fmaxf(m, B[j]);         \
    if (lane == 63) m = fmaxf(m, B16);                                         \
    if (m > 0.f) {                                                             \
      int e = (int)((__float_as_uint(m) >> 23) & 255u);                        \
      int shift = 127 - e;                                                     \
      _Pragma("unroll") for (int j = 0; j < 16; ++j) B[j] = ldexpf(B[j], shift); \
      B16 = ldexpf(B16, shift);                                                \
      omega += shift;                                                          \
    } else {                                                                   \
      omega = wprev;                                                           \
    }                                                                          \
    wprev = __shfl_up(omega, 1, 64);                                           \
    wd = omega - wprev;                                                        \
    Lraw = __shfl_up(B[15], 1, 64);                                            \
    ++t;                                                                       \
  }

  for (int g = 0; g < 511; ++g) {   // steps t = 8g+1 .. 8g+8 (1..4088)
    STEPF_N(a, a16, b, b16, qa0, qb0, e0);
    STEPF_N(b, b16, a, a16, qa1, qb1, e1);
    STEPF_N(a, a16, b, b16, qa2, qb2, e2);
    STEPF_N(b, b16, a, a16, qa3, qb3, e3);
    STEPF_N(a, a16, b, b16, qa4, qb4, e4);
    STEPF_N(b, b16, a, a16, qa5, qb5, e5);
    STEPF_N(a, a16, b, b16, qa6, qb6, e6);
    STEPS_N(b, b16, a, a16, qa7, qb7, e7);   // rescale at t=8g+8; ends in a
  }
  // steps t = 4089 .. 4095 (7 steps; result ends in b).
  // PREFN reads rows 4097..4103 -- covered by 64-row slack in ws.
  STEPF_N(a, a16, b, b16, qa0, qb0, e0);
  STEPF_N(b, b16, a, a16, qa1, qb1, e1);
  STEPF_N(a, a16, b, b16, qa2, qb2, e2);
  STEPF_N(b, b16, a, a16, qa3, qb3, e3);
  STEPF_N(a, a16, b, b16, qa4, qb4, e4);
  STEPF_N(b, b16, a, a16, qa5, qb5, e5);
  STEPF_N(a, a16, b, b16, qa6, qb6, e6);

  if (lane == 63) {
    // states 1023 (b[15]) and 1024 (b16), lane-63 scale: 2^(sc - omega)
    float tot = b[15] + b16;
    out[0] = -LN2F * (FLOG2(tot) + sc - (float)omega);
  }
}

extern "C" void kernel_launch(void* const* d_in, const int* in_sizes, int n_in,
                              void* d_out, int out_size, void* d_ws, size_t ws_size,
                              hipStream_t stream) {
  (void)in_sizes; (void)n_in; (void)out_size; (void)ws_size;
  const float* logits = (const float*)d_in[0];
  const int* targets = (const int*)d_in[1];
  // ws layout: P bf16 [4096 x 1026] (8,404,992 B) | 64 rows slack (prefetch
  // overrun, contents unused) | cvec f32[4096]
  char* ws = (char*)d_ws;
  __hip_bfloat16* P = (__hip_bfloat16*)ws;
  float* cvec = (float*)(ws + (size_t)T_STEPS * PROWB + 64 * PROWB);

  ctc_emit<<<dim3(T_STEPS), dim3(256), 0, stream>>>(logits, targets, P, cvec);
  ctc_scan1w<<<dim3(1), dim3(64), 0, stream>>>((const char*)P, cvec, targets,
                                               (float*)d_out);
}